// Round 1
// baseline (8687.714 us; speedup 1.0000x reference)
//
#include <hip/hip_runtime.h>
#include <hip/hip_cooperative_groups.h>

namespace cg = cooperative_groups;

#define B_   32
#define T_   32
#define VIS_ 1024
#define FF_  512
#define LAT_ 512
#define ACT_ 8
#define OUTSTRIDE (33 * 512)   // (T+1)*LAT per batch row

__device__ __forceinline__ float dot512(const float* __restrict__ x, const float* __restrict__ w) {
  const float4* x4 = (const float4*)x;
  const float4* w4 = (const float4*)w;
  float a0 = 0.f, a1 = 0.f, a2 = 0.f, a3 = 0.f;
#pragma unroll 8
  for (int k = 0; k < 128; ++k) {
    float4 a = x4[k], b = w4[k];
    a0 += a.x * b.x; a1 += a.y * b.y; a2 += a.z * b.z; a3 += a.w * b.w;
  }
  return (a0 + a1) + (a2 + a3);
}

__device__ __forceinline__ float dot1024(const float* __restrict__ x, const float* __restrict__ w) {
  const float4* x4 = (const float4*)x;
  const float4* w4 = (const float4*)w;
  float a0 = 0.f, a1 = 0.f, a2 = 0.f, a3 = 0.f;
#pragma unroll 8
  for (int k = 0; k < 256; ++k) {
    float4 a = x4[k], b = w4[k];
    a0 += a.x * b.x; a1 += a.y * b.y; a2 += a.z * b.z; a3 += a.w * b.w;
  }
  return (a0 + a1) + (a2 + a3);
}

__device__ __forceinline__ float sigmoidf_(float x) { return 1.f / (1.f + expf(-x)); }
__device__ __forceinline__ float softplusf_(float x) { return (x > 20.f) ? x : log1pf(expf(x)); }

// ---------------------------------------------------------------------------
// K1a: mean-pool img_feat (B,T,VIS,6,8) over last 48 elems -> pooled (B*T, VIS)
// one block per (b,t); thread v sums its channels (48 contiguous floats each)
// ---------------------------------------------------------------------------
__global__ void pool_kernel(const float* __restrict__ img, float* __restrict__ pooled) {
  int bt = blockIdx.x;
  const float* src = img + (size_t)bt * (VIS_ * 48);
  float* dst = pooled + (size_t)bt * VIS_;
  for (int v = threadIdx.x; v < VIS_; v += blockDim.x) {
    const float4* p4 = (const float4*)(src + v * 48);
    float s = 0.f;
#pragma unroll
    for (int k = 0; k < 12; ++k) { float4 a = p4[k]; s += (a.x + a.y) + (a.z + a.w); }
    dst[v] = s * (1.f / 48.f);
  }
}

// ---------------------------------------------------------------------------
// K1b: obs_enc[bt,f] = pooled[bt,:] . W_obs[f,:] + b_obs[f]     (K=1024)
// grid: 2048 blocks = 128 row-octets x 16 f-slices; 256 thr = 8 rows x 32 f
// ---------------------------------------------------------------------------
__global__ void obs_gemm(const float* __restrict__ pooled, const float* __restrict__ W_obs,
                         const float* __restrict__ b_obs, float* __restrict__ obs_enc) {
  int oct = blockIdx.x >> 4;
  int fs  = blockIdx.x & 15;
  int r   = threadIdx.x & 7;
  int f   = fs * 32 + (threadIdx.x >> 3);
  int bt  = oct * 8 + r;
  float d = dot1024(pooled + (size_t)bt * VIS_, W_obs + (size_t)f * VIS_) + b_obs[f];
  obs_enc[(size_t)bt * FF_ + f] = d;
}

// ---------------------------------------------------------------------------
// K2: P[bt,f]   = obs_enc[bt,:] . W_post1[f, FF:2FF] + b_post1[f]   (K=512)
//     apre[bt,f]= actions[bt,:] . W_gi[f, LAT:LAT+8] + b_gi[f]      (K=8)
// ---------------------------------------------------------------------------
__global__ void p_gemm(const float* __restrict__ obs_enc, const float* __restrict__ actions,
                       const float* __restrict__ W_post1, const float* __restrict__ b_post1,
                       const float* __restrict__ W_gi, const float* __restrict__ b_gi,
                       float* __restrict__ P, float* __restrict__ apre) {
  int oct = blockIdx.x >> 4;
  int fs  = blockIdx.x & 15;
  int r   = threadIdx.x & 7;
  int f   = fs * 32 + (threadIdx.x >> 3);
  int bt  = oct * 8 + r;
  float d = dot512(obs_enc + (size_t)bt * FF_, W_post1 + (size_t)f * (2 * FF_) + FF_) + b_post1[f];
  P[(size_t)bt * FF_ + f] = d;
  const float* a  = actions + (size_t)bt * ACT_;
  const float* wg = W_gi + (size_t)f * (LAT_ + ACT_) + LAT_;
  float av = b_gi[f];
#pragma unroll
  for (int j = 0; j < ACT_; ++j) av += a[j] * wg[j];
  apre[(size_t)bt * FF_ + f] = av;
}

// ---------------------------------------------------------------------------
// Cooperative scan kernel: 128 blocks x 512 threads = 65536 threads.
// Job layout: r = tid&31 (batch row), c = tid>>5 (output column 0..2047).
// Lanes 0-31 of each wave share c -> weight row loads are half-wave broadcast.
// ---------------------------------------------------------------------------
struct ScanParams {
  const float* eps0; const float* eps_seq; const float* init_hidden;
  const float* W_post1;
  const float* W_pm; const float* b_pm; const float* W_ps; const float* b_ps;
  const float* W_gi;
  const float* Wih; const float* Whh; const float* bih; const float* bhh;
  const float* W_pr1; const float* b_pr1;
  const float* W_prm; const float* b_prm; const float* W_prs; const float* b_prs;
  const float* P; const float* apre;
  float* out; float* gi; float* gh; float* gx; float* h0; float* h1; float* mid;
};

__global__ void __launch_bounds__(512) scan_kernel(ScanParams p) {
  cg::grid_group grid = cg::this_grid();
  const int tid   = blockIdx.x * blockDim.x + threadIdx.x;
  const int r     = tid & 31;
  const int c_all = tid >> 5;   // 0..2047

  // pre-stage: h0 rows = init_hidden (broadcast); mid = relu(P[:,0,:]) (belief=0)
  if (c_all < 512) {
    p.h0[r * 512 + c_all] = p.init_hidden[c_all];
  } else if (c_all < 1024) {
    int c = c_all - 512;
    p.mid[r * 512 + c] = fmaxf(p.P[(r * T_ + 0) * 512 + c], 0.f);
  }
  grid.sync();

  // s0 = (mid@W_pm.T + b_pm) + (softplus(mid@W_ps.T + b_ps)+0.01) * eps0
  if (c_all < 512) {
    int c = c_all;
    float mean = dot512(p.mid + r * 512, p.W_pm + (size_t)c * 512) + p.b_pm[c];
    float sv   = softplusf_(dot512(p.mid + r * 512, p.W_ps + (size_t)c * 512) + p.b_ps[c]) + 0.01f;
    p.out[r * OUTSTRIDE + c] = mean + sv * p.eps0[r * 512 + c];
  }
  grid.sync();

  for (int t = 0; t < T_; ++t) {
    const float* h_prev = (t & 1) ? p.h1 : p.h0;
    float*       h_next = (t & 1) ? p.h0 : p.h1;
    const float* s_prev = p.out + t * 512;   // + r*OUTSTRIDE

    // Stage A: gi = relu(s_prev @ Wgi_s.T + apre[t]);  gh = h_prev @ Whh.T + bhh
    if (c_all < 512) {
      int c = c_all;
      float d = dot512(s_prev + r * OUTSTRIDE, p.W_gi + (size_t)c * (LAT_ + ACT_))
              + p.apre[(r * T_ + t) * 512 + c];
      p.gi[r * 512 + c] = fmaxf(d, 0.f);
    } else {
      int c = c_all - 512;   // 0..1535
      p.gh[r * 1536 + c] = dot512(h_prev + r * 512, p.Whh + (size_t)c * 512) + p.bhh[c];
    }
    grid.sync();

    // Stage B1: gx = gi @ Wih.T + bih
    if (c_all < 1536) {
      int c = c_all;
      p.gx[r * 1536 + c] = dot512(p.gi + r * 512, p.Wih + (size_t)c * 512) + p.bih[c];
    }
    grid.sync();

    // Stage B2: GRU elementwise -> h_next
    if (c_all < 512) {
      int v = c_all;
      float xr = p.gx[r * 1536 + v], xz = p.gx[r * 1536 + 512 + v], xn = p.gx[r * 1536 + 1024 + v];
      float hr = p.gh[r * 1536 + v], hz = p.gh[r * 1536 + 512 + v], hn = p.gh[r * 1536 + 1024 + v];
      float hv = h_prev[r * 512 + v];
      float rg = sigmoidf_(xr + hr);
      float zg = sigmoidf_(xz + hz);
      float nn = tanhf(xn + rg * hn);
      h_next[r * 512 + v] = (1.f - zg) * nn + zg * hv;
    }
    grid.sync();

    // Stage C: mid = relu(h_next @ W.T + add); posterior for t<T-1, prior at last
    if (c_all < 512) {
      int c = c_all;
      float d;
      if (t < T_ - 1) {
        d = dot512(h_next + r * 512, p.W_post1 + (size_t)c * (2 * FF_))
          + p.P[(r * T_ + t + 1) * 512 + c];
      } else {
        d = dot512(h_next + r * 512, p.W_pr1 + (size_t)c * 512) + p.b_pr1[c];
      }
      p.mid[r * 512 + c] = fmaxf(d, 0.f);
    }
    grid.sync();

    // Stage D: mean/std GEMMs + sample; write out[:, t+1, :]
    if (c_all < 512) {
      int c = c_all;
      const float *Wm, *Ws, *bm, *bs;
      if (t < T_ - 1) { Wm = p.W_pm; Ws = p.W_ps; bm = p.b_pm; bs = p.b_ps; }
      else            { Wm = p.W_prm; Ws = p.W_prs; bm = p.b_prm; bs = p.b_prs; }
      float mean = dot512(p.mid + r * 512, Wm + (size_t)c * 512) + bm[c];
      float sv   = softplusf_(dot512(p.mid + r * 512, Ws + (size_t)c * 512) + bs[c]) + 0.01f;
      p.out[r * OUTSTRIDE + (t + 1) * 512 + c] =
          mean + sv * p.eps_seq[(t * B_ + r) * 512 + c];
    }
    grid.sync();
  }
}

extern "C" void kernel_launch(void* const* d_in, const int* in_sizes, int n_in,
                              void* d_out, int out_size, void* d_ws, size_t ws_size,
                              hipStream_t stream) {
  const float* img      = (const float*)d_in[0];
  const float* actions  = (const float*)d_in[1];
  const float* eps0     = (const float*)d_in[2];
  const float* eps_seq  = (const float*)d_in[3];
  const float* init_h   = (const float*)d_in[4];
  const float* W_obs    = (const float*)d_in[5];
  const float* b_obs    = (const float*)d_in[6];
  const float* W_post1  = (const float*)d_in[7];
  const float* b_post1  = (const float*)d_in[8];
  const float* W_pm     = (const float*)d_in[9];
  const float* b_pm     = (const float*)d_in[10];
  const float* W_ps     = (const float*)d_in[11];
  const float* b_ps     = (const float*)d_in[12];
  const float* W_gi     = (const float*)d_in[13];
  const float* b_gi     = (const float*)d_in[14];
  const float* Wih      = (const float*)d_in[15];
  const float* Whh      = (const float*)d_in[16];
  const float* bih      = (const float*)d_in[17];
  const float* bhh      = (const float*)d_in[18];
  const float* W_pr1    = (const float*)d_in[19];
  const float* b_pr1    = (const float*)d_in[20];
  const float* W_prm    = (const float*)d_in[21];
  const float* b_prm    = (const float*)d_in[22];
  const float* W_prs    = (const float*)d_in[23];
  const float* b_prs    = (const float*)d_in[24];

  float* ws      = (float*)d_ws;
  float* pooled  = ws;                              // 1024*1024
  float* obs_enc = pooled  + 1024 * 1024;           // 1024*512
  float* P       = obs_enc + 1024 * 512;            // 1024*512
  float* apre    = P       + 1024 * 512;            // 1024*512
  float* gi      = apre    + 1024 * 512;            // 32*512
  float* gh      = gi      + 32 * 512;              // 32*1536
  float* gx      = gh      + 32 * 1536;             // 32*1536
  float* h0      = gx      + 32 * 1536;             // 32*512
  float* h1      = h0      + 32 * 512;              // 32*512
  float* mid     = h1      + 32 * 512;              // 32*512

  pool_kernel<<<dim3(B_ * T_), dim3(256), 0, stream>>>(img, pooled);
  obs_gemm<<<dim3(2048), dim3(256), 0, stream>>>(pooled, W_obs, b_obs, obs_enc);
  p_gemm<<<dim3(2048), dim3(256), 0, stream>>>(obs_enc, actions, W_post1, b_post1,
                                               W_gi, b_gi, P, apre);

  ScanParams sp;
  sp.eps0 = eps0; sp.eps_seq = eps_seq; sp.init_hidden = init_h;
  sp.W_post1 = W_post1;
  sp.W_pm = W_pm; sp.b_pm = b_pm; sp.W_ps = W_ps; sp.b_ps = b_ps;
  sp.W_gi = W_gi;
  sp.Wih = Wih; sp.Whh = Whh; sp.bih = bih; sp.bhh = bhh;
  sp.W_pr1 = W_pr1; sp.b_pr1 = b_pr1;
  sp.W_prm = W_prm; sp.b_prm = b_prm; sp.W_prs = W_prs; sp.b_prs = b_prs;
  sp.P = P; sp.apre = apre;
  sp.out = (float*)d_out;
  sp.gi = gi; sp.gh = gh; sp.gx = gx; sp.h0 = h0; sp.h1 = h1; sp.mid = mid;

  void* kargs[] = { &sp };
  hipLaunchCooperativeKernel(reinterpret_cast<void*>(scan_kernel),
                             dim3(128), dim3(512), kargs, 0, stream);
}

// Round 2
// 4713.246 us; speedup vs baseline: 1.8433x; 1.8433x over previous
//
#include <hip/hip_runtime.h>
#include <hip/hip_cooperative_groups.h>

namespace cg = cooperative_groups;

#define B_   32
#define T_   32
#define VIS_ 1024
#define FF_  512
#define OUTSTRIDE (33 * 512)

__device__ __forceinline__ float bflo(unsigned u){ return __uint_as_float(u << 16); }
__device__ __forceinline__ float bfhi(unsigned u){ return __uint_as_float(u & 0xffff0000u); }
__device__ __forceinline__ unsigned f2bf(float f){
  unsigned u = __float_as_uint(f);
  return (u + 0x7fffu + ((u >> 16) & 1u)) >> 16;   // RNE
}
__device__ __forceinline__ float sigmoidf_(float x){ return 1.f / (1.f + expf(-x)); }
__device__ __forceinline__ float softplusf_(float x){ return (x > 20.f) ? x : log1pf(expf(x)); }

// dot over K = 4*K4: weights k-major packed bf16 pairs, x fp32 broadcast
template<int K4>
__device__ __forceinline__ float dotT(const uint2* __restrict__ wt, int C, int c,
                                      const float4* __restrict__ x){
  float a0=0.f, a1=0.f, a2=0.f, a3=0.f;
  const uint2* wp = wt + c;
#pragma unroll 8
  for (int k4 = 0; k4 < K4; ++k4){
    uint2 w = wp[(size_t)k4 * C];
    float4 xv = x[k4];
    a0 = fmaf(bflo(w.x), xv.x, a0);
    a1 = fmaf(bfhi(w.x), xv.y, a1);
    a2 = fmaf(bflo(w.y), xv.z, a2);
    a3 = fmaf(bfhi(w.y), xv.w, a3);
  }
  return (a0 + a1) + (a2 + a3);
}

// fused double dot sharing x loads
template<int K4>
__device__ __forceinline__ float2 dotT2(const uint2* __restrict__ wa,
                                        const uint2* __restrict__ wb, int C, int c,
                                        const float4* __restrict__ x){
  float a0=0.f, a1=0.f, a2=0.f, a3=0.f;
  float b0=0.f, b1=0.f, b2=0.f, b3=0.f;
  const uint2* wpa = wa + c;
  const uint2* wpb = wb + c;
#pragma unroll 4
  for (int k4 = 0; k4 < K4; ++k4){
    uint2 u = wpa[(size_t)k4 * C];
    uint2 v = wpb[(size_t)k4 * C];
    float4 xv = x[k4];
    a0 = fmaf(bflo(u.x), xv.x, a0);
    a1 = fmaf(bfhi(u.x), xv.y, a1);
    a2 = fmaf(bflo(u.y), xv.z, a2);
    a3 = fmaf(bfhi(u.y), xv.w, a3);
    b0 = fmaf(bflo(v.x), xv.x, b0);
    b1 = fmaf(bfhi(v.x), xv.y, b1);
    b2 = fmaf(bflo(v.y), xv.z, b2);
    b3 = fmaf(bfhi(v.y), xv.w, b3);
  }
  float2 r; r.x = (a0+a1)+(a2+a3); r.y = (b0+b1)+(b2+b3);
  return r;
}

// ---------------------------------------------------------------------------
// Weight transpose+bf16 pack: src fp32 [C][rowStride] (cols colOff..colOff+4*K4)
// -> dst u2 [k4][C]. 11 segments packed contiguously; dst[i] with i global.
// ---------------------------------------------------------------------------
struct TP {
  const float* src[11];
  unsigned C[11], stride[11], colOff[11];
  unsigned segStart[12];
};

__global__ void __launch_bounds__(512) transpose_bf16(TP tp, uint2* __restrict__ dst){
  unsigned i = blockIdx.x * 512u + threadIdx.x;   // exactly 1<<20 threads
  int s = 0;
#pragma unroll
  for (int q = 1; q < 11; ++q) if (i >= tp.segStart[q]) s = q;
  unsigned local = i - tp.segStart[s];
  unsigned C = tp.C[s];
  unsigned c  = local % C;
  unsigned k4 = local / C;
  const float* sp = tp.src[s] + (size_t)c * tp.stride[s] + tp.colOff[s] + k4 * 4u;
  float4 v = *(const float4*)sp;
  uint2 o;
  o.x = f2bf(v.x) | (f2bf(v.y) << 16);
  o.y = f2bf(v.z) | (f2bf(v.w) << 16);
  dst[i] = o;
}

// action-part of W_gi, fp32 transposed [8][512]
__global__ void wgact_fill(const float* __restrict__ W_gi, float* __restrict__ wgact){
  int f = threadIdx.x;
#pragma unroll
  for (int jj = 0; jj < 8; ++jj) wgact[jj * 512 + f] = W_gi[f * 520 + 512 + jj];
}

// ---------------------------------------------------------------------------
// mean-pool img (B,T,1024,6,8) -> pooled (B*T,1024). 4 lanes per channel.
// ---------------------------------------------------------------------------
__global__ void __launch_bounds__(512) pool2(const float* __restrict__ img,
                                             float* __restrict__ pooled){
  int bt = blockIdx.x;
  int chb = threadIdx.x >> 2;      // 0..127
  int m   = threadIdx.x & 3;
  const float* src = img + (size_t)bt * (VIS_ * 48);
#pragma unroll
  for (int i = 0; i < 8; ++i){
    int ch = chb + i * 128;
    const float4* p4 = (const float4*)(src + ch * 48 + m * 12);
    float4 a = p4[0], b = p4[1], c = p4[2];
    float sv = (a.x+a.y)+(a.z+a.w) + (b.x+b.y)+(b.z+b.w) + (c.x+c.y)+(c.z+c.w);
    sv += __shfl_xor(sv, 1);
    sv += __shfl_xor(sv, 2);
    if (m == 0) pooled[(size_t)bt * VIS_ + ch] = sv * (1.f / 48.f);
  }
}

// obs_enc = pooled @ W_obs.T + b_obs    (K=1024, via wtObs k-major)
__global__ void __launch_bounds__(512) obs2(const float* __restrict__ pooled,
    const uint2* __restrict__ wtObs, const float* __restrict__ b_obs,
    float* __restrict__ obs_enc){
  int bt = blockIdx.x;
  int f  = threadIdx.x;
  float d = dotT<256>(wtObs, 512, f, (const float4*)(pooled + (size_t)bt * VIS_)) + b_obs[f];
  obs_enc[(size_t)bt * 512 + f] = d;
}

// P = obs_enc @ W_post1[:,512:].T + b_post1 ; apre = actions @ Wgi_act.T + b_gi
__global__ void __launch_bounds__(512) pgemm2(const float* __restrict__ obs_enc,
    const float* __restrict__ actions, const uint2* __restrict__ wtP1o,
    const float* __restrict__ b_post1, const float* __restrict__ wgact,
    const float* __restrict__ b_gi, float* __restrict__ P, float* __restrict__ apre){
  int bt = blockIdx.x;
  int f  = threadIdx.x;
  P[(size_t)bt * 512 + f] =
      dotT<128>(wtP1o, 512, f, (const float4*)(obs_enc + (size_t)bt * 512)) + b_post1[f];
  float av = b_gi[f];
  const float* a = actions + (size_t)bt * 8;
#pragma unroll
  for (int jj = 0; jj < 8; ++jj) av = fmaf(a[jj], wgact[jj * 512 + f], av);
  apre[(size_t)bt * 512 + f] = av;
}

// ---------------------------------------------------------------------------
// Cooperative scan: 128 blocks x 512 thr. Wave = (one row r, 64 consecutive c)
// -> x loads are same-address broadcasts, weight loads coalesced.
// block b: r-range = (b&3)*8 + wave, c-chunk = (b>>2)*64.
// ---------------------------------------------------------------------------
struct ScanP {
  const uint2 *wtP1h, *wtGi, *wtWhh, *wtWih, *wtPm, *wtPs, *wtPr1, *wtPrm, *wtPrs;
  const float *P, *apre, *eps0, *eps_seq, *init_h;
  const float *bhh, *bih, *b_pr1, *b_pm, *b_ps, *b_prm, *b_prs;
  float *out, *gi, *gh, *gx, *h, *mid;
};

__global__ void __launch_bounds__(512) scan2(ScanP p){
  cg::grid_group g = cg::this_grid();
  const int b  = blockIdx.x;
  const int j  = threadIdx.x >> 6;
  const int l  = threadIdx.x & 63;
  const int r  = (b & 3) * 8 + j;
  const int c  = (b >> 2) * 64 + l;      // 0..2047

  // P0: mid0 = relu(P[:,0,:]) (belief = 0), h = init_hidden
  if (c < 512){
    p.mid[r * 512 + c] = fmaxf(p.P[(r * T_ + 0) * 512 + c], 0.f);
    p.h[r * 512 + c]   = p.init_h[c];
  }
  g.sync();
  // s0
  if (c < 512){
    float2 ms = dotT2<128>(p.wtPm, p.wtPs, 512, c, (const float4*)(p.mid + r * 512));
    float mean = ms.x + p.b_pm[c];
    float sd   = softplusf_(ms.y + p.b_ps[c]) + 0.01f;
    p.out[r * OUTSTRIDE + c] = mean + sd * p.eps0[r * 512 + c];
  }

  for (int t = 0; t < T_; ++t){
    g.sync();
    // A: gi = relu(s_prev@WgiT + apre) ; gh = h@WhhT + bhh
    if (c < 512){
      float d = dotT<128>(p.wtGi, 512, c, (const float4*)(p.out + r * OUTSTRIDE + t * 512))
              + p.apre[(r * T_ + t) * 512 + c];
      p.gi[r * 512 + c] = fmaxf(d, 0.f);
    } else {
      int c2 = c - 512;   // 0..1535
      p.gh[r * 1536 + c2] =
          dotT<128>(p.wtWhh, 1536, c2, (const float4*)(p.h + r * 512)) + p.bhh[c2];
    }
    g.sync();
    // B: gx = gi@WihT + bih
    if (c < 1536)
      p.gx[r * 1536 + c] =
          dotT<128>(p.wtWih, 1536, c, (const float4*)(p.gi + r * 512)) + p.bih[c];
    g.sync();
    // B2: GRU elementwise (in-place h update; each thread touches only its own h)
    if (c < 512){
      float xr = p.gx[r*1536 + c], xz = p.gx[r*1536 + 512 + c], xn = p.gx[r*1536 + 1024 + c];
      float hr = p.gh[r*1536 + c], hz = p.gh[r*1536 + 512 + c], hn = p.gh[r*1536 + 1024 + c];
      float hv = p.h[r*512 + c];
      float rg = sigmoidf_(xr + hr);
      float zg = sigmoidf_(xz + hz);
      float nn = tanhf(xn + rg * hn);
      p.h[r*512 + c] = (1.f - zg) * nn + zg * hv;
    }
    g.sync();
    // C: mid = relu(h@W.T + add)   (posterior for t<T-1, prior last)
    if (c < 512){
      float d;
      if (t < T_ - 1)
        d = dotT<128>(p.wtP1h, 512, c, (const float4*)(p.h + r*512)) + p.P[(r*T_ + t + 1)*512 + c];
      else
        d = dotT<128>(p.wtPr1, 512, c, (const float4*)(p.h + r*512)) + p.b_pr1[c];
      p.mid[r*512 + c] = fmaxf(d, 0.f);
    }
    g.sync();
    // DE: mean/std + sample
    if (c < 512){
      const uint2* Wm = (t < T_-1) ? p.wtPm : p.wtPrm;
      const uint2* Ws = (t < T_-1) ? p.wtPs : p.wtPrs;
      const float* bm = (t < T_-1) ? p.b_pm : p.b_prm;
      const float* bs = (t < T_-1) ? p.b_ps : p.b_prs;
      float2 ms = dotT2<128>(Wm, Ws, 512, c, (const float4*)(p.mid + r*512));
      float mean = ms.x + bm[c];
      float sd   = softplusf_(ms.y + bs[c]) + 0.01f;
      p.out[r*OUTSTRIDE + (t+1)*512 + c] = mean + sd * p.eps_seq[(t*B_ + r)*512 + c];
    }
  }
}

extern "C" void kernel_launch(void* const* d_in, const int* in_sizes, int n_in,
                              void* d_out, int out_size, void* d_ws, size_t ws_size,
                              hipStream_t stream) {
  const float* img      = (const float*)d_in[0];
  const float* actions  = (const float*)d_in[1];
  const float* eps0     = (const float*)d_in[2];
  const float* eps_seq  = (const float*)d_in[3];
  const float* init_h   = (const float*)d_in[4];
  const float* W_obs    = (const float*)d_in[5];
  const float* b_obs    = (const float*)d_in[6];
  const float* W_post1  = (const float*)d_in[7];
  const float* b_post1  = (const float*)d_in[8];
  const float* W_pm     = (const float*)d_in[9];
  const float* b_pm     = (const float*)d_in[10];
  const float* W_ps     = (const float*)d_in[11];
  const float* b_ps     = (const float*)d_in[12];
  const float* W_gi     = (const float*)d_in[13];
  const float* b_gi     = (const float*)d_in[14];
  const float* Wih      = (const float*)d_in[15];
  const float* Whh      = (const float*)d_in[16];
  const float* bih      = (const float*)d_in[17];
  const float* bhh      = (const float*)d_in[18];
  const float* W_pr1    = (const float*)d_in[19];
  const float* b_pr1    = (const float*)d_in[20];
  const float* W_prm    = (const float*)d_in[21];
  const float* b_prm    = (const float*)d_in[22];
  const float* W_prs    = (const float*)d_in[23];
  const float* b_prs    = (const float*)d_in[24];

  // ws layout
  float* ws       = (float*)d_ws;
  uint2* wt       = (uint2*)ws;                 // 1048576 u2 = 2097152 floats
  float* wgact    = ws + 2097152;               // 4096
  float* pooled   = wgact + 4096;               // 1048576
  float* obs_enc  = pooled + 1048576;           // 524288
  float* P        = obs_enc + 524288;           // 524288
  float* apre     = P + 524288;                 // 524288
  float* gi       = apre + 524288;              // 16384
  float* gh       = gi + 16384;                 // 49152
  float* gx       = gh + 49152;                 // 49152
  float* h        = gx + 49152;                 // 16384
  float* mid      = h + 16384;                  // 16384

  // wt segment offsets (u2 units)
  const unsigned OBS = 0, P1O = 131072, P1H = 196608, GI = 262144, WHH = 327680,
                 WIH = 524288, PM = 720896, PS = 786432, PR1 = 851968,
                 PRM = 917504, PRS = 983040, END = 1048576;

  TP tp;
  const float* srcs[11]  = {W_obs, W_post1, W_post1, W_gi, Whh, Wih, W_pm, W_ps, W_pr1, W_prm, W_prs};
  unsigned Cs[11]        = {512, 512, 512, 512, 1536, 1536, 512, 512, 512, 512, 512};
  unsigned strides[11]   = {1024, 1024, 1024, 520, 512, 512, 512, 512, 512, 512, 512};
  unsigned colOffs[11]   = {0, 512, 0, 0, 0, 0, 0, 0, 0, 0, 0};
  unsigned starts[12]    = {OBS, P1O, P1H, GI, WHH, WIH, PM, PS, PR1, PRM, PRS, END};
  for (int i = 0; i < 11; ++i){
    tp.src[i] = srcs[i]; tp.C[i] = Cs[i]; tp.stride[i] = strides[i]; tp.colOff[i] = colOffs[i];
  }
  for (int i = 0; i < 12; ++i) tp.segStart[i] = starts[i];

  transpose_bf16<<<dim3(2048), dim3(512), 0, stream>>>(tp, wt);
  wgact_fill<<<dim3(1), dim3(512), 0, stream>>>(W_gi, wgact);
  pool2<<<dim3(B_ * T_), dim3(512), 0, stream>>>(img, pooled);
  obs2<<<dim3(B_ * T_), dim3(512), 0, stream>>>(pooled, wt + OBS, b_obs, obs_enc);
  pgemm2<<<dim3(B_ * T_), dim3(512), 0, stream>>>(obs_enc, actions, wt + P1O, b_post1,
                                                  wgact, b_gi, P, apre);

  ScanP sp;
  sp.wtP1h = wt + P1H; sp.wtGi = wt + GI; sp.wtWhh = wt + WHH; sp.wtWih = wt + WIH;
  sp.wtPm = wt + PM; sp.wtPs = wt + PS; sp.wtPr1 = wt + PR1; sp.wtPrm = wt + PRM; sp.wtPrs = wt + PRS;
  sp.P = P; sp.apre = apre; sp.eps0 = eps0; sp.eps_seq = eps_seq; sp.init_h = init_h;
  sp.bhh = bhh; sp.bih = bih; sp.b_pr1 = b_pr1; sp.b_pm = b_pm; sp.b_ps = b_ps;
  sp.b_prm = b_prm; sp.b_prs = b_prs;
  sp.out = (float*)d_out;
  sp.gi = gi; sp.gh = gh; sp.gx = gx; sp.h = h; sp.mid = mid;

  void* kargs[] = { &sp };
  hipLaunchCooperativeKernel(reinterpret_cast<void*>(scan2),
                             dim3(128), dim3(512), kargs, 0, stream);
}